// Round 2
// baseline (94.020 us; speedup 1.0000x reference)
//
#include <hip/hip_runtime.h>
#include <math.h>

// HiddenTreeMarkovModel upward recursion.
// T_TREES=128, BR=2, DEPTH=11, C=8, L=2, M=256, G=4.
// Grid = 256 blocks: block = (tree t, g-pair). Each block handles g in
// {g0, g0+1}, g0 = 2*(blockIdx.x & 1), t = blockIdx.x >> 1.
// Global level offsets: offs[l] = 128*(2^l - 1); within a level tree t owns
// [offs[l] + t*2^l, +2^l). Parent of within-tree child k at level l is k>>1.
//
// Stage 1 fuses levels 11,10,9 (7-node subtree per thread, all in registers).
// Stage 2 walks levels 9->0 with ping-pong LDS beta buffers.
// LDS ~70 KB -> 1024 threads, 16 waves, 1 block/CU, grid fills all 256 CUs.

#define NTHREADS 1024
#define NSTRIDE 17   // per-node floats in beta buffers: 2 g's x 8 c, +1 pad (odd)

__global__ __launch_bounds__(NTHREADS) void htmm_kernel(
    const float* __restrict__ lA,   // (C,C,L,G)  c*64 + d*8 + p*4 + g
    const float* __restrict__ lB,   // (C,M,G)    c*1024 + m*4 + g
    const float* __restrict__ lPi,  // (C,L,G)    c*8 + p*4 + g
    const float* __restrict__ lSP,  // (L,G)      p*4 + g
    const int* __restrict__ pos,
    const int* __restrict__ xx,
    float* __restrict__ out)        // (128,4)
{
    __shared__ float sBm[16 * 256];       // [(c*2+gi)][m]
    __shared__ float sA[256];             // [((p*2+gi)*8+c)*8+d]
    __shared__ float sPi[32];             // [(p*2+gi)*8+c]
    __shared__ float sSP[4];              // [p*2+gi]
    __shared__ float sInv[16];
    __shared__ float buf0[512 * NSTRIDE]; // levels 9,7,5,3,1
    __shared__ float buf1[256 * NSTRIDE]; // levels 8,6,4,2,0
    __shared__ double sLL[2];

    const int tid = threadIdx.x;
    const int t  = blockIdx.x >> 1;
    const int g0 = (blockIdx.x & 1) << 1;

    if (tid < 2) sLL[tid] = 0.0;

    // ---------- softmax tables (only our 2 g's) ----------
    // Bm exp pass: 4096 elems
#pragma unroll
    for (int k = 0; k < 4; ++k) {
        int idx = tid + k * NTHREADS;
        int c = idx >> 9, m = (idx >> 1) & 255, gi = idx & 1;
        sBm[((c << 1) | gi) * 256 + m] = expf(lB[c * 1024 + m * 4 + g0 + gi]);
    }
    __syncthreads();

    if (tid < 256) {
        // parallel row sums: 16 rows x 16 segments of 16, staggered (<=4-way)
        int r = tid >> 4, seg = tid & 15;
        float s = 0.f;
#pragma unroll
        for (int i = 0; i < 16; ++i) s += sBm[r * 256 + seg * 16 + ((i + seg) & 15)];
#pragma unroll
        for (int o = 8; o >= 1; o >>= 1) s += __shfl_xor(s, o, 64);
        if (seg == 0) sInv[r] = 1.0f / s;
    } else if (tid >= 256 && tid < 288) {
        // A softmax over c, per (d,p,gi)
        int w = tid - 256;
        int d = w >> 2, pp = (w >> 1) & 1, gi = w & 1;
        float e[8]; float s = 0.f;
#pragma unroll
        for (int c = 0; c < 8; ++c) { e[c] = expf(lA[c * 64 + d * 8 + pp * 4 + g0 + gi]); s += e[c]; }
        float inv = 1.f / s;
#pragma unroll
        for (int c = 0; c < 8; ++c) sA[(((pp << 1) | gi) * 8 + c) * 8 + d] = e[c] * inv;
    } else if (tid >= 288 && tid < 292) {
        // Pi softmax over c, per (p,gi)
        int w = tid - 288; int pp = w >> 1, gi = w & 1;
        float e[8]; float s = 0.f;
#pragma unroll
        for (int c = 0; c < 8; ++c) { e[c] = expf(lPi[c * 8 + pp * 4 + g0 + gi]); s += e[c]; }
        float inv = 1.f / s;
#pragma unroll
        for (int c = 0; c < 8; ++c) sPi[((pp << 1) | gi) * 8 + c] = e[c] * inv;
    } else if (tid >= 292 && tid < 294) {
        int gi = tid - 292;
        float e0 = expf(lSP[g0 + gi]), e1 = expf(lSP[4 + g0 + gi]);
        float inv = 1.f / (e0 + e1);
        sSP[gi] = e0 * inv; sSP[2 + gi] = e1 * inv;
    }
    __syncthreads();

    // Bm normalize
#pragma unroll
    for (int k = 0; k < 4; ++k) {
        int idx = tid + k * NTHREADS;
        sBm[idx] *= sInv[idx >> 8];
    }
    __syncthreads();

    float ll0 = 0.f, ll1 = 0.f;   // per-thread log-likelihood partials per gi

    // ---------- stage 1: fused levels 11,10,9 ----------
    {
        const int j  = tid & 511;      // level-9 node within tree
        const int gi = tid >> 9;       // wave-uniform
        const int4 pv4 = *(const int4*)(pos + 262016 + t * 2048 + 4 * j);
        const int4 xv4 = *(const int4*)(xx  + 262016 + t * 2048 + 4 * j);
        const int2 pu2 = *(const int2*)(pos + 130944 + t * 1024 + 2 * j);
        const int2 xu2 = *(const int2*)(xx  + 130944 + t * 1024 + 2 * j);
        const int xq = xx[65408 + t * 512 + j];

        float llacc = 0.f;
        float tq[8] = {0,0,0,0,0,0,0,0};
#pragma unroll
        for (int u = 0; u < 2; ++u) {
            float tu[8] = {0,0,0,0,0,0,0,0};
#pragma unroll
            for (int v = 0; v < 2; ++v) {
                const int k = 2 * u + v;
                const int pv  = (k == 0) ? pv4.x : (k == 1) ? pv4.y : (k == 2) ? pv4.z : pv4.w;
                const int xvv = (k == 0) ? xv4.x : (k == 1) ? xv4.y : (k == 2) ? xv4.z : xv4.w;
                const float* Pip = &sPi[((pv << 1) | gi) << 3];
                float b[8]; float nu = 0.f;
#pragma unroll
                for (int c = 0; c < 8; ++c) {
                    b[c] = Pip[c] * sBm[((c << 1) | gi) * 256 + xvv];
                    nu += b[c];
                }
                llacc += logf(nu);
                const float scale = sSP[(pv << 1) | gi] / nu;   // fold normalization
                const float* Ap = &sA[((pv << 1) | gi) << 6];
#pragma unroll
                for (int c = 0; c < 8; ++c) {
                    float s = 0.f;
#pragma unroll
                    for (int d = 0; d < 8; ++d) s += Ap[(c << 3) + d] * b[d];
                    tu[c] += scale * s;
                }
            }
            const int pu = u ? pu2.y : pu2.x;
            const int xu = u ? xu2.y : xu2.x;
            float bu[8]; float nuu = 0.f;
#pragma unroll
            for (int c = 0; c < 8; ++c) { bu[c] = tu[c] * sBm[((c << 1) | gi) * 256 + xu]; nuu += bu[c]; }
            llacc += logf(nuu);
            const float scale = sSP[(pu << 1) | gi] / nuu;
            const float* Ap = &sA[((pu << 1) | gi) << 6];
#pragma unroll
            for (int c = 0; c < 8; ++c) {
                float s = 0.f;
#pragma unroll
                for (int d = 0; d < 8; ++d) s += Ap[(c << 3) + d] * bu[d];
                tq[c] += scale * s;
            }
        }
        float bq[8]; float nuq = 0.f;
#pragma unroll
        for (int c = 0; c < 8; ++c) { bq[c] = tq[c] * sBm[((c << 1) | gi) * 256 + xq]; nuq += bq[c]; }
        llacc += logf(nuq);
        const float inv = 1.f / nuq;
#pragma unroll
        for (int c = 0; c < 8; ++c) buf0[j * NSTRIDE + (gi << 3) + c] = bq[c] * inv;

        if (gi == 0) ll0 += llacc; else ll1 += llacc;
    }
    __syncthreads();

    // ---------- stage 2: levels 9 -> 0 ----------
    float* bin = buf0;
    float* bout = buf1;
    for (int l = 9; l >= 1; --l) {
        const int nP = 1 << (l - 1);
        const int nItems = nP << 1;               // (parents) x (2 g's)
        const int chBase = 128 * ((1 << l) - 1) + t * (1 << l);
        const int paBase = 128 * (nP - 1) + t * nP;
        if (tid < nItems) {
            const int p  = tid & (nP - 1);
            const int gi = tid >> (l - 1);
            const int2 pch = *(const int2*)(pos + chBase + 2 * p);
            const int xpa = xx[paBase + p];
            float tp[8] = {0,0,0,0,0,0,0,0};
#pragma unroll
            for (int u = 0; u < 2; ++u) {
                const int pw = u ? pch.y : pch.x;
                const float* bip = &bin[(2 * p + u) * NSTRIDE + (gi << 3)];
                float b[8];
#pragma unroll
                for (int d = 0; d < 8; ++d) b[d] = bip[d];
                const float scale = sSP[(pw << 1) | gi];
                const float* Ap = &sA[((pw << 1) | gi) << 6];
#pragma unroll
                for (int c = 0; c < 8; ++c) {
                    float s = 0.f;
#pragma unroll
                    for (int d = 0; d < 8; ++d) s += Ap[(c << 3) + d] * b[d];
                    tp[c] += scale * s;
                }
            }
            float bpv[8]; float nu = 0.f;
#pragma unroll
            for (int c = 0; c < 8; ++c) { bpv[c] = tp[c] * sBm[((c << 1) | gi) * 256 + xpa]; nu += bpv[c]; }
            const float llv = logf(nu);
            const float inv = 1.f / nu;
#pragma unroll
            for (int c = 0; c < 8; ++c) bout[p * NSTRIDE + (gi << 3) + c] = bpv[c] * inv;
            if (gi == 0) ll0 += llv; else ll1 += llv;
        }
        __syncthreads();
        float* tmpp = bin; bin = bout; bout = tmpp;
    }

    // ---------- final log-likelihood reduction ----------
    float r0 = ll0, r1 = ll1;
#pragma unroll
    for (int o = 32; o >= 1; o >>= 1) {
        r0 += __shfl_xor(r0, o, 64);
        r1 += __shfl_xor(r1, o, 64);
    }
    if ((tid & 63) == 0) {
        atomicAdd(&sLL[0], (double)r0);
        atomicAdd(&sLL[1], (double)r1);
    }
    __syncthreads();
    if (tid < 2) out[(t << 2) + g0 + tid] = (float)sLL[tid];
}

extern "C" void kernel_launch(void* const* d_in, const int* in_sizes, int n_in,
                              void* d_out, int out_size, void* d_ws, size_t ws_size,
                              hipStream_t stream) {
    const float* lA  = (const float*)d_in[0];
    const float* lB  = (const float*)d_in[1];
    const float* lPi = (const float*)d_in[2];
    const float* lSP = (const float*)d_in[3];
    const int*   pos = (const int*)d_in[4];
    const int*   xv  = (const int*)d_in[5];
    float* out = (float*)d_out;
    htmm_kernel<<<256, NTHREADS, 0, stream>>>(lA, lB, lPi, lSP, pos, xv, out);
}